// Round 2
// baseline (434.217 us; speedup 1.0000x reference)
//
#include <hip/hip_runtime.h>

#define CAP 128

typedef __attribute__((ext_vector_type(8))) short bf16x8;
typedef __attribute__((ext_vector_type(4))) float f32x4;

__device__ __forceinline__ unsigned short f2bf(float f) {
    unsigned u = __float_as_uint(f);
    u += 0x7FFFu + ((u >> 16) & 1u);
    return (unsigned short)(u >> 16);
}
__device__ __forceinline__ float bf2f(unsigned short h) {
    return __uint_as_float(((unsigned)h) << 16);
}

// ---------------- fp32 -> bf16 conversion (hp, hq, 12 weights) ----------------
struct CvtSeg { const float* s; unsigned short* d; int n4; };
struct CvtArgs { CvtSeg seg[14]; };

__global__ __launch_bounds__(256) void cvt_kernel(CvtArgs c) {
    int gid = blockIdx.x * 256 + threadIdx.x;
    int stride = gridDim.x * 256;
    #pragma unroll
    for (int si = 0; si < 14; ++si) {
        CvtSeg sg = c.seg[si];
        for (int i = gid; i < sg.n4; i += stride) {
            float4 v = ((const float4*)sg.s)[i];
            ushort4 o;
            o.x = f2bf(v.x); o.y = f2bf(v.y); o.z = f2bf(v.z); o.w = f2bf(v.w);
            ((ushort4*)sg.d)[i] = o;
        }
    }
}

// ---------------- dense 0/1 adjacency -> per-row index lists ----------------
// One WAVE per row, grid-strided. No LDS, no barriers. Per 2048-elem chunk:
// 8 coalesced float4 loads -> 32-bit nonzero mask/lane -> popc + shfl_up wave
// scan -> ffs-driven scatter (skips zeros entirely).
struct ExtArgs { const float* a0; const float* a1; const float* a2; const float* a3; int* idx; int* cnt; };

__global__ __launch_bounds__(256) void extract_kernel(ExtArgs e) {
    int lane = threadIdx.x & 63;
    int gw = (blockIdx.x * 256 + threadIdx.x) >> 6;
    const int NW = (2048 * 256) >> 6;               // 8192 waves
    for (int rw = gw; rw < 4 * 8192; rw += NW) {
        int m = rw >> 13;
        int row = rw & 8191;
        const float* A = (m == 0) ? e.a0 : (m == 1) ? e.a1 : (m == 2) ? e.a2 : e.a3;
        const float4* rp = (const float4*)(A + (size_t)row * 8192);
        int* op = e.idx + (size_t)rw * CAP;
        int base = 0;
        #pragma unroll
        for (int c = 0; c < 4; ++c) {
            float4 v[8];
            #pragma unroll
            for (int it = 0; it < 8; ++it)
                v[it] = rp[c * 512 + it * 64 + lane];      // 1 KB/wave per instr
            unsigned mask = 0;
            #pragma unroll
            for (int it = 0; it < 8; ++it) {
                mask |= (unsigned)(v[it].x != 0.f) << (4 * it);
                mask |= (unsigned)(v[it].y != 0.f) << (4 * it + 1);
                mask |= (unsigned)(v[it].z != 0.f) << (4 * it + 2);
                mask |= (unsigned)(v[it].w != 0.f) << (4 * it + 3);
            }
            int cnt = __popc(mask);
            int pre = cnt;                                  // inclusive scan over 64 lanes
            #pragma unroll
            for (int off = 1; off < 64; off <<= 1) {
                int t = __shfl_up(pre, off);
                if (lane >= off) pre += t;
            }
            int tot = __shfl(pre, 63);
            int myoff = base + pre - cnt;                   // exclusive
            while (mask) {
                int b = __ffs((int)mask) - 1;
                mask &= mask - 1;
                int j = c * 2048 + (b >> 2) * 256 + lane * 4 + (b & 3);
                if (myoff < CAP) op[myoff] = j;
                myoff++;
            }
            base += tot;
        }
        if (lane == 0) e.cnt[rw] = base < CAP ? base : CAP;
    }
}

// ---------------- 6 linears in one launch: Z = bf16(X @ W^T + b) ----------------
struct GemmDesc { const unsigned short* X; const unsigned short* W; const float* bias; unsigned short* Z; };
struct GemmArgs { GemmDesc d[6]; };

template<int K>
__global__ __launch_bounds__(256) void gemm6_kernel(GemmArgs ga) {
    GemmDesc g = ga.d[blockIdx.z];
    int wave = threadIdx.x >> 6;
    int lane = threadIdx.x & 63;
    int r = lane & 15, q = lane >> 4;
    int rowbase = blockIdx.x * 128 + wave * 32;   // 64 blocks * 128 rows = 8192
    int colbase = blockIdx.y * 64;                // 4 blocks * 64 cols = 256
    f32x4 acc[2][4] = {};
    const unsigned short* xp0 = g.X + (size_t)(rowbase + r) * K + q * 8;
    const unsigned short* xp1 = xp0 + (size_t)16 * K;
    const unsigned short* wbase = g.W + (size_t)(colbase + r) * K + q * 8;
    #pragma unroll
    for (int k0 = 0; k0 < K; k0 += 32) {
        bf16x8 a0 = *(const bf16x8*)(xp0 + k0);
        bf16x8 a1 = *(const bf16x8*)(xp1 + k0);
        #pragma unroll
        for (int nt = 0; nt < 4; ++nt) {
            bf16x8 b = *(const bf16x8*)(wbase + (size_t)nt * 16 * K + k0);
            acc[0][nt] = __builtin_amdgcn_mfma_f32_16x16x32_bf16(a0, b, acc[0][nt], 0, 0, 0);
            acc[1][nt] = __builtin_amdgcn_mfma_f32_16x16x32_bf16(a1, b, acc[1][nt], 0, 0, 0);
        }
    }
    // C/D layout: col = lane&15, row = (lane>>4)*4 + reg   [guide §3, m89-verified]
    #pragma unroll
    for (int mt = 0; mt < 2; ++mt) {
        #pragma unroll
        for (int nt = 0; nt < 4; ++nt) {
            int col = colbase + nt * 16 + r;
            float bv = g.bias[col];
            #pragma unroll
            for (int j = 0; j < 4; ++j) {
                int row = rowbase + mt * 16 + q * 4 + j;
                g.Z[(size_t)row * 256 + col] = f2bf(acc[mt][nt][j] + bv);
            }
        }
    }
}

// ---------------- fused self + 2 SpMM gathers + leaky_relu (+ optional L2-norm) ----------------
// Half-wave (32 lanes) per output row: 16 B/lane gathers, neighbor indices
// preloaded to registers and broadcast via __shfl, a/b chains interleaved.
struct AggSide {
    const unsigned short* zself;
    const unsigned short* za;
    const unsigned short* zb;
    const int* idxa; const int* cnta;
    const int* idxb; const int* cntb;
    unsigned short* out_bf;
    float* out_f;
};

template<int FINAL>
__global__ __launch_bounds__(256) void agg_kernel(AggSide s0, AggSide s1) {
    AggSide s = blockIdx.y ? s1 : s0;
    int wave = threadIdx.x >> 6, lane = threadIdx.x & 63;
    int h = lane >> 5, l32 = lane & 31;
    int row = blockIdx.x * 8 + wave * 2 + h;      // 1024 blocks * 8 rows
    int c8 = l32 * 8;                             // 8 bf16 cols per lane
    bf16x8 v = *(const bf16x8*)(s.zself + (size_t)row * 256 + c8);
    float acc[8];
    #pragma unroll
    for (int j = 0; j < 8; ++j) acc[j] = bf2f((unsigned short)v[j]);
    int ca = s.cnta[row], cb = s.cntb[row];
    const int* ia = s.idxa + (size_t)row * CAP;
    const int* ib = s.idxb + (size_t)row * CAP;
    int ra0 = ia[l32], ra1 = ia[32 + l32], ra2 = ia[64 + l32], ra3 = ia[96 + l32];
    int rb0 = ib[l32], rb1 = ib[32 + l32], rb2 = ib[64 + l32], rb3 = ib[96 + l32];
    int cm = ca > cb ? ca : cb;
    #pragma unroll
    for (int p = 0; p < 4; ++p) {
        if (cm > p * 32) {
            int lim = cm - p * 32; if (lim > 32) lim = 32;
            int rap = (p == 0) ? ra0 : (p == 1) ? ra1 : (p == 2) ? ra2 : ra3;
            int rbp = (p == 0) ? rb0 : (p == 1) ? rb1 : (p == 2) ? rb2 : rb3;
            #pragma unroll 2
            for (int k = 0; k < lim; ++k) {
                int kk = p * 32 + k;
                int na = __shfl(rap, h * 32 + k);
                int nb = __shfl(rbp, h * 32 + k);
                if (kk < ca) {
                    bf16x8 w = *(const bf16x8*)(s.za + (size_t)na * 256 + c8);
                    #pragma unroll
                    for (int j = 0; j < 8; ++j) acc[j] += bf2f((unsigned short)w[j]);
                }
                if (kk < cb) {
                    bf16x8 w = *(const bf16x8*)(s.zb + (size_t)nb * 256 + c8);
                    #pragma unroll
                    for (int j = 0; j < 8; ++j) acc[j] += bf2f((unsigned short)w[j]);
                }
            }
        }
    }
    #pragma unroll
    for (int j = 0; j < 8; ++j) acc[j] = acc[j] > 0.f ? acc[j] : 0.1f * acc[j];
    if (FINAL) {
        float ss = 0.f;
        #pragma unroll
        for (int j = 0; j < 8; ++j) ss += acc[j] * acc[j];
        #pragma unroll
        for (int off = 1; off < 32; off <<= 1) ss += __shfl_xor(ss, off);
        float sc = 1.0f / (sqrtf(ss) + 1e-9f);
        float4 o0, o1;
        o0.x = acc[0] * sc; o0.y = acc[1] * sc; o0.z = acc[2] * sc; o0.w = acc[3] * sc;
        o1.x = acc[4] * sc; o1.y = acc[5] * sc; o1.z = acc[6] * sc; o1.w = acc[7] * sc;
        float* op = s.out_f + (size_t)row * 256 + c8;
        *(float4*)op = o0;
        *(float4*)(op + 4) = o1;
    } else {
        bf16x8 o;
        #pragma unroll
        for (int j = 0; j < 8; ++j) o[j] = (short)f2bf(acc[j]);
        *(bf16x8*)(s.out_bf + (size_t)row * 256 + c8) = o;
    }
}

extern "C" void kernel_launch(void* const* d_in, const int* in_sizes, int n_in,
                              void* d_out, int out_size, void* d_ws, size_t ws_size,
                              hipStream_t stream) {
    const float* hp         = (const float*)d_in[0];
    const float* hq         = (const float*)d_in[1];
    const float* a_cons     = (const float*)d_in[2];
    const float* a_prod     = (const float*)d_in[3];
    const float* a_rev_cons = (const float*)d_in[4];
    const float* a_rev_prod = (const float*)d_in[5];

    char* ws = (char*)d_ws;
    constexpr size_t SZ_H   = (size_t)8192 * 512 * 2;   // bf16 hp/hq
    constexpr size_t SZ_W1  = (size_t)256 * 512 * 2;
    constexpr size_t SZ_W2  = (size_t)256 * 256 * 2;
    constexpr size_t SZ_Z   = (size_t)8192 * 256 * 2;   // bf16 z / h1
    constexpr size_t OFF_HP  = 0;
    constexpr size_t OFF_HQ  = OFF_HP + SZ_H;
    constexpr size_t OFF_WBF = OFF_HQ + SZ_H;
    constexpr size_t OFF_IDX = OFF_WBF + 6 * SZ_W1 + 6 * SZ_W2;
    constexpr size_t OFF_CNT = OFF_IDX + (size_t)4 * 8192 * CAP * 4;
    constexpr size_t OFF_Z   = OFF_CNT + (size_t)4 * 8192 * 4;
    constexpr size_t OFF_H1P = OFF_Z + 6 * SZ_Z;
    constexpr size_t OFF_H1Q = OFF_H1P + SZ_Z;

    unsigned short* hp_bf = (unsigned short*)(ws + OFF_HP);
    unsigned short* hq_bf = (unsigned short*)(ws + OFF_HQ);
    int* idx = (int*)(ws + OFF_IDX);
    int* cnt = (int*)(ws + OFF_CNT);
    unsigned short* z[6];
    for (int i = 0; i < 6; ++i) z[i] = (unsigned short*)(ws + OFF_Z + i * SZ_Z);
    unsigned short* h1p = (unsigned short*)(ws + OFF_H1P);
    unsigned short* h1q = (unsigned short*)(ws + OFF_H1Q);

    // bf16 weight slots: l1: 0 wp1, 1 wcons1, 2 wrprod1, 3 wq1, 4 wprod1, 5 wrcons1
    //                    l2: 6 wp2, 7 wcons2, 8 wrprod2, 9 wq2, 10 wprod2, 11 wrcons2
    unsigned short* wbf[12];
    for (int i = 0; i < 6; ++i) wbf[i]     = (unsigned short*)(ws + OFF_WBF + i * SZ_W1);
    for (int i = 0; i < 6; ++i) wbf[6 + i] = (unsigned short*)(ws + OFF_WBF + 6 * SZ_W1 + i * SZ_W2);

    CvtArgs ca;
    ca.seg[0] = { hp, hp_bf, 8192 * 512 / 4 };
    ca.seg[1] = { hq, hq_bf, 8192 * 512 / 4 };
    const int wIdxL1[6] = { 6, 10, 12, 8, 14, 16 };   // wp1, wcons1, wrprod1, wq1, wprod1, wrcons1
    const int wIdxL2[6] = { 18, 22, 24, 20, 26, 28 }; // wp2, wcons2, wrprod2, wq2, wprod2, wrcons2
    for (int i = 0; i < 6; ++i) ca.seg[2 + i] = { (const float*)d_in[wIdxL1[i]], wbf[i],     256 * 512 / 4 };
    for (int i = 0; i < 6; ++i) ca.seg[8 + i] = { (const float*)d_in[wIdxL2[i]], wbf[6 + i], 256 * 256 / 4 };
    cvt_kernel<<<dim3(1024), dim3(256), 0, stream>>>(ca);

    ExtArgs ea = { a_cons, a_prod, a_rev_cons, a_rev_prod, idx, cnt };
    extract_kernel<<<dim3(2048), dim3(256), 0, stream>>>(ea);

    // layer 1 linears (K=512)
    GemmArgs g1;
    g1.d[0] = { hp_bf, wbf[0], (const float*)d_in[7],  z[0] };
    g1.d[1] = { hq_bf, wbf[1], (const float*)d_in[11], z[1] };
    g1.d[2] = { hq_bf, wbf[2], (const float*)d_in[13], z[2] };
    g1.d[3] = { hq_bf, wbf[3], (const float*)d_in[9],  z[3] };
    g1.d[4] = { hp_bf, wbf[4], (const float*)d_in[15], z[4] };
    g1.d[5] = { hp_bf, wbf[5], (const float*)d_in[17], z[5] };
    gemm6_kernel<512><<<dim3(64, 4, 6), dim3(256), 0, stream>>>(g1);

    int* idx0 = idx + (size_t)0 * 8192 * CAP;  // a_cons      (P rows over Q)
    int* idx1 = idx + (size_t)1 * 8192 * CAP;  // a_prod      (Q rows over P)
    int* idx2 = idx + (size_t)2 * 8192 * CAP;  // a_rev_cons  (Q rows over P)
    int* idx3 = idx + (size_t)3 * 8192 * CAP;  // a_rev_prod  (P rows over Q)
    int* cnt0 = cnt, *cnt1 = cnt + 8192, *cnt2 = cnt + 16384, *cnt3 = cnt + 24576;

    AggSide p1 = { z[0], z[1], z[2], idx0, cnt0, idx3, cnt3, h1p, nullptr };
    AggSide q1 = { z[3], z[4], z[5], idx1, cnt1, idx2, cnt2, h1q, nullptr };
    agg_kernel<0><<<dim3(1024, 2), dim3(256), 0, stream>>>(p1, q1);

    // layer 2 linears (K=256)
    GemmArgs g2;
    g2.d[0] = { h1p, wbf[6],  (const float*)d_in[19], z[0] };
    g2.d[1] = { h1q, wbf[7],  (const float*)d_in[23], z[1] };
    g2.d[2] = { h1q, wbf[8],  (const float*)d_in[25], z[2] };
    g2.d[3] = { h1q, wbf[9],  (const float*)d_in[21], z[3] };
    g2.d[4] = { h1p, wbf[10], (const float*)d_in[27], z[4] };
    g2.d[5] = { h1p, wbf[11], (const float*)d_in[29], z[5] };
    gemm6_kernel<256><<<dim3(64, 4, 6), dim3(256), 0, stream>>>(g2);

    float* outp = (float*)d_out;
    AggSide p2 = { z[0], z[1], z[2], idx0, cnt0, idx3, cnt3, nullptr, outp };
    AggSide q2 = { z[3], z[4], z[5], idx1, cnt1, idx2, cnt2, nullptr, outp + (size_t)8192 * 256 };
    agg_kernel<1><<<dim3(1024, 2), dim3(256), 0, stream>>>(p2, q2);
}

// Round 3
// 383.596 us; speedup vs baseline: 1.1320x; 1.1320x over previous
//
#include <hip/hip_runtime.h>

#define CAP 128

typedef __attribute__((ext_vector_type(8))) short bf16x8;
typedef __attribute__((ext_vector_type(4))) float f32x4;
typedef __attribute__((ext_vector_type(4))) float f32x4v;

__device__ __forceinline__ unsigned short f2bf(float f) {
    unsigned u = __float_as_uint(f);
    u += 0x7FFFu + ((u >> 16) & 1u);
    return (unsigned short)(u >> 16);
}
__device__ __forceinline__ float bf2f(unsigned short h) {
    return __uint_as_float(((unsigned)h) << 16);
}

// ---------------- fp32 -> bf16 conversion (hp, hq, 12 weights) ----------------
struct CvtSeg { const float* s; unsigned short* d; int n4; };
struct CvtArgs { CvtSeg seg[14]; };

__global__ __launch_bounds__(256) void cvt_kernel(CvtArgs c) {
    int gid = blockIdx.x * 256 + threadIdx.x;
    int stride = gridDim.x * 256;
    #pragma unroll
    for (int si = 0; si < 14; ++si) {
        CvtSeg sg = c.seg[si];
        for (int i = gid; i < sg.n4; i += stride) {
            float4 v = ((const float4*)sg.s)[i];
            ushort4 o;
            o.x = f2bf(v.x); o.y = f2bf(v.y); o.z = f2bf(v.z); o.w = f2bf(v.w);
            ((ushort4*)sg.d)[i] = o;
        }
    }
}

// ---------------- dense 0/1 adjacency -> per-row index lists ----------------
// Block (256 thr, 4 waves) per row. Each thread: 8 nontemporal float4 loads
// folded into a 32-bit nonzero mask (no vals[] kept -> no spill). Compaction:
// 6-step shfl_up wave scan + ONE barrier for 4 wave totals, then ffs scatter.
struct ExtArgs { const float* a0; const float* a1; const float* a2; const float* a3; int* idx; int* cnt; };

__global__ __launch_bounds__(256) void extract_kernel(ExtArgs e) {
    int row = blockIdx.x, m = blockIdx.y, t = threadIdx.x;
    int wave = t >> 6, lane = t & 63;
    const float* A = (m == 0) ? e.a0 : (m == 1) ? e.a1 : (m == 2) ? e.a2 : e.a3;
    const f32x4v* rp = (const f32x4v*)(A + (size_t)row * 8192);
    unsigned mask = 0;
    #pragma unroll
    for (int it = 0; it < 8; ++it) {
        f32x4v v = __builtin_nontemporal_load(&rp[it * 256 + t]);   // 4 KB/instr per block, read-once
        mask |= (unsigned)(v.x != 0.f) << (4 * it);
        mask |= (unsigned)(v.y != 0.f) << (4 * it + 1);
        mask |= (unsigned)(v.z != 0.f) << (4 * it + 2);
        mask |= (unsigned)(v.w != 0.f) << (4 * it + 3);
    }
    int cnt = __popc(mask);
    int pre = cnt;                       // inclusive scan within wave
    #pragma unroll
    for (int off = 1; off < 64; off <<= 1) {
        int u = __shfl_up(pre, off);
        if (lane >= off) pre += u;
    }
    __shared__ int lwt[4];
    if (lane == 63) lwt[wave] = pre;
    __syncthreads();
    int wbase = 0;
    if (wave > 0) wbase += lwt[0];
    if (wave > 1) wbase += lwt[1];
    if (wave > 2) wbase += lwt[2];
    int o = wbase + pre - cnt;           // block-level exclusive prefix
    int* op = e.idx + ((size_t)m * 8192 + row) * CAP;
    while (mask) {
        int b = __ffs((int)mask) - 1;
        mask &= mask - 1;
        int j = (b >> 2) * 1024 + t * 4 + (b & 3);
        if (o < CAP) op[o] = j;
        o++;
    }
    if (t == 0) {
        int tot = lwt[0] + lwt[1] + lwt[2] + lwt[3];
        e.cnt[m * 8192 + row] = tot < CAP ? tot : CAP;
    }
}

// ---------------- 6 linears in one launch: Z = bf16(X @ W^T + b) ----------------
struct GemmDesc { const unsigned short* X; const unsigned short* W; const float* bias; unsigned short* Z; };
struct GemmArgs { GemmDesc d[6]; };

template<int K>
__global__ __launch_bounds__(256) void gemm6_kernel(GemmArgs ga) {
    GemmDesc g = ga.d[blockIdx.z];
    int wave = threadIdx.x >> 6;
    int lane = threadIdx.x & 63;
    int r = lane & 15, q = lane >> 4;
    int rowbase = blockIdx.x * 128 + wave * 32;   // 64 blocks * 128 rows = 8192
    int colbase = blockIdx.y * 64;                // 4 blocks * 64 cols = 256
    f32x4 acc[2][4] = {};
    const unsigned short* xp0 = g.X + (size_t)(rowbase + r) * K + q * 8;
    const unsigned short* xp1 = xp0 + (size_t)16 * K;
    const unsigned short* wbase = g.W + (size_t)(colbase + r) * K + q * 8;
    #pragma unroll
    for (int k0 = 0; k0 < K; k0 += 32) {
        bf16x8 a0 = *(const bf16x8*)(xp0 + k0);
        bf16x8 a1 = *(const bf16x8*)(xp1 + k0);
        #pragma unroll
        for (int nt = 0; nt < 4; ++nt) {
            bf16x8 b = *(const bf16x8*)(wbase + (size_t)nt * 16 * K + k0);
            acc[0][nt] = __builtin_amdgcn_mfma_f32_16x16x32_bf16(a0, b, acc[0][nt], 0, 0, 0);
            acc[1][nt] = __builtin_amdgcn_mfma_f32_16x16x32_bf16(a1, b, acc[1][nt], 0, 0, 0);
        }
    }
    // C/D layout: col = lane&15, row = (lane>>4)*4 + reg   [guide §3, m89-verified]
    #pragma unroll
    for (int mt = 0; mt < 2; ++mt) {
        #pragma unroll
        for (int nt = 0; nt < 4; ++nt) {
            int col = colbase + nt * 16 + r;
            float bv = g.bias[col];
            #pragma unroll
            for (int j = 0; j < 4; ++j) {
                int row = rowbase + mt * 16 + q * 4 + j;
                g.Z[(size_t)row * 256 + col] = f2bf(acc[mt][nt][j] + bv);
            }
        }
    }
}

// ---------------- fused self + 2 SpMM gathers + leaky_relu (+ optional L2-norm) ----------------
// Half-wave (32 lanes) per output row: 16 B/lane gathers, neighbor indices
// preloaded to registers and broadcast via __shfl, a/b chains interleaved.
struct AggSide {
    const unsigned short* zself;
    const unsigned short* za;
    const unsigned short* zb;
    const int* idxa; const int* cnta;
    const int* idxb; const int* cntb;
    unsigned short* out_bf;
    float* out_f;
};

template<int FINAL>
__global__ __launch_bounds__(256) void agg_kernel(AggSide s0, AggSide s1) {
    AggSide s = blockIdx.y ? s1 : s0;
    int wave = threadIdx.x >> 6, lane = threadIdx.x & 63;
    int h = lane >> 5, l32 = lane & 31;
    int row = blockIdx.x * 8 + wave * 2 + h;      // 1024 blocks * 8 rows
    int c8 = l32 * 8;                             // 8 bf16 cols per lane
    bf16x8 v = *(const bf16x8*)(s.zself + (size_t)row * 256 + c8);
    float acc[8];
    #pragma unroll
    for (int j = 0; j < 8; ++j) acc[j] = bf2f((unsigned short)v[j]);
    int ca = s.cnta[row], cb = s.cntb[row];
    const int* ia = s.idxa + (size_t)row * CAP;
    const int* ib = s.idxb + (size_t)row * CAP;
    int ra0 = ia[l32], ra1 = ia[32 + l32], ra2 = ia[64 + l32], ra3 = ia[96 + l32];
    int rb0 = ib[l32], rb1 = ib[32 + l32], rb2 = ib[64 + l32], rb3 = ib[96 + l32];
    int cm = ca > cb ? ca : cb;
    #pragma unroll
    for (int p = 0; p < 4; ++p) {
        if (cm > p * 32) {
            int lim = cm - p * 32; if (lim > 32) lim = 32;
            int rap = (p == 0) ? ra0 : (p == 1) ? ra1 : (p == 2) ? ra2 : ra3;
            int rbp = (p == 0) ? rb0 : (p == 1) ? rb1 : (p == 2) ? rb2 : rb3;
            #pragma unroll 2
            for (int k = 0; k < lim; ++k) {
                int kk = p * 32 + k;
                int na = __shfl(rap, h * 32 + k);
                int nb = __shfl(rbp, h * 32 + k);
                if (kk < ca) {
                    bf16x8 w = *(const bf16x8*)(s.za + (size_t)na * 256 + c8);
                    #pragma unroll
                    for (int j = 0; j < 8; ++j) acc[j] += bf2f((unsigned short)w[j]);
                }
                if (kk < cb) {
                    bf16x8 w = *(const bf16x8*)(s.zb + (size_t)nb * 256 + c8);
                    #pragma unroll
                    for (int j = 0; j < 8; ++j) acc[j] += bf2f((unsigned short)w[j]);
                }
            }
        }
    }
    #pragma unroll
    for (int j = 0; j < 8; ++j) acc[j] = acc[j] > 0.f ? acc[j] : 0.1f * acc[j];
    if (FINAL) {
        float ss = 0.f;
        #pragma unroll
        for (int j = 0; j < 8; ++j) ss += acc[j] * acc[j];
        #pragma unroll
        for (int off = 1; off < 32; off <<= 1) ss += __shfl_xor(ss, off);
        float sc = 1.0f / (sqrtf(ss) + 1e-9f);
        float4 o0, o1;
        o0.x = acc[0] * sc; o0.y = acc[1] * sc; o0.z = acc[2] * sc; o0.w = acc[3] * sc;
        o1.x = acc[4] * sc; o1.y = acc[5] * sc; o1.z = acc[6] * sc; o1.w = acc[7] * sc;
        float* op = s.out_f + (size_t)row * 256 + c8;
        *(float4*)op = o0;
        *(float4*)(op + 4) = o1;
    } else {
        bf16x8 o;
        #pragma unroll
        for (int j = 0; j < 8; ++j) o[j] = (short)f2bf(acc[j]);
        *(bf16x8*)(s.out_bf + (size_t)row * 256 + c8) = o;
    }
}

extern "C" void kernel_launch(void* const* d_in, const int* in_sizes, int n_in,
                              void* d_out, int out_size, void* d_ws, size_t ws_size,
                              hipStream_t stream) {
    const float* hp         = (const float*)d_in[0];
    const float* hq         = (const float*)d_in[1];
    const float* a_cons     = (const float*)d_in[2];
    const float* a_prod     = (const float*)d_in[3];
    const float* a_rev_cons = (const float*)d_in[4];
    const float* a_rev_prod = (const float*)d_in[5];

    char* ws = (char*)d_ws;
    constexpr size_t SZ_H   = (size_t)8192 * 512 * 2;   // bf16 hp/hq
    constexpr size_t SZ_W1  = (size_t)256 * 512 * 2;
    constexpr size_t SZ_W2  = (size_t)256 * 256 * 2;
    constexpr size_t SZ_Z   = (size_t)8192 * 256 * 2;   // bf16 z / h1
    constexpr size_t OFF_HP  = 0;
    constexpr size_t OFF_HQ  = OFF_HP + SZ_H;
    constexpr size_t OFF_WBF = OFF_HQ + SZ_H;
    constexpr size_t OFF_IDX = OFF_WBF + 6 * SZ_W1 + 6 * SZ_W2;
    constexpr size_t OFF_CNT = OFF_IDX + (size_t)4 * 8192 * CAP * 4;
    constexpr size_t OFF_Z   = OFF_CNT + (size_t)4 * 8192 * 4;
    constexpr size_t OFF_H1P = OFF_Z + 6 * SZ_Z;
    constexpr size_t OFF_H1Q = OFF_H1P + SZ_Z;

    unsigned short* hp_bf = (unsigned short*)(ws + OFF_HP);
    unsigned short* hq_bf = (unsigned short*)(ws + OFF_HQ);
    int* idx = (int*)(ws + OFF_IDX);
    int* cnt = (int*)(ws + OFF_CNT);
    unsigned short* z[6];
    for (int i = 0; i < 6; ++i) z[i] = (unsigned short*)(ws + OFF_Z + i * SZ_Z);
    unsigned short* h1p = (unsigned short*)(ws + OFF_H1P);
    unsigned short* h1q = (unsigned short*)(ws + OFF_H1Q);

    // bf16 weight slots: l1: 0 wp1, 1 wcons1, 2 wrprod1, 3 wq1, 4 wprod1, 5 wrcons1
    //                    l2: 6 wp2, 7 wcons2, 8 wrprod2, 9 wq2, 10 wprod2, 11 wrcons2
    unsigned short* wbf[12];
    for (int i = 0; i < 6; ++i) wbf[i]     = (unsigned short*)(ws + OFF_WBF + i * SZ_W1);
    for (int i = 0; i < 6; ++i) wbf[6 + i] = (unsigned short*)(ws + OFF_WBF + 6 * SZ_W1 + i * SZ_W2);

    CvtArgs ca;
    ca.seg[0] = { hp, hp_bf, 8192 * 512 / 4 };
    ca.seg[1] = { hq, hq_bf, 8192 * 512 / 4 };
    const int wIdxL1[6] = { 6, 10, 12, 8, 14, 16 };   // wp1, wcons1, wrprod1, wq1, wprod1, wrcons1
    const int wIdxL2[6] = { 18, 22, 24, 20, 26, 28 }; // wp2, wcons2, wrprod2, wq2, wprod2, wrcons2
    for (int i = 0; i < 6; ++i) ca.seg[2 + i] = { (const float*)d_in[wIdxL1[i]], wbf[i],     256 * 512 / 4 };
    for (int i = 0; i < 6; ++i) ca.seg[8 + i] = { (const float*)d_in[wIdxL2[i]], wbf[6 + i], 256 * 256 / 4 };
    cvt_kernel<<<dim3(1024), dim3(256), 0, stream>>>(ca);

    ExtArgs ea = { a_cons, a_prod, a_rev_cons, a_rev_prod, idx, cnt };
    extract_kernel<<<dim3(8192, 4), dim3(256), 0, stream>>>(ea);

    // layer 1 linears (K=512)
    GemmArgs g1;
    g1.d[0] = { hp_bf, wbf[0], (const float*)d_in[7],  z[0] };
    g1.d[1] = { hq_bf, wbf[1], (const float*)d_in[11], z[1] };
    g1.d[2] = { hq_bf, wbf[2], (const float*)d_in[13], z[2] };
    g1.d[3] = { hq_bf, wbf[3], (const float*)d_in[9],  z[3] };
    g1.d[4] = { hp_bf, wbf[4], (const float*)d_in[15], z[4] };
    g1.d[5] = { hp_bf, wbf[5], (const float*)d_in[17], z[5] };
    gemm6_kernel<512><<<dim3(64, 4, 6), dim3(256), 0, stream>>>(g1);

    int* idx0 = idx + (size_t)0 * 8192 * CAP;  // a_cons      (P rows over Q)
    int* idx1 = idx + (size_t)1 * 8192 * CAP;  // a_prod      (Q rows over P)
    int* idx2 = idx + (size_t)2 * 8192 * CAP;  // a_rev_cons  (Q rows over P)
    int* idx3 = idx + (size_t)3 * 8192 * CAP;  // a_rev_prod  (P rows over Q)
    int* cnt0 = cnt, *cnt1 = cnt + 8192, *cnt2 = cnt + 16384, *cnt3 = cnt + 24576;

    AggSide p1 = { z[0], z[1], z[2], idx0, cnt0, idx3, cnt3, h1p, nullptr };
    AggSide q1 = { z[3], z[4], z[5], idx1, cnt1, idx2, cnt2, h1q, nullptr };
    agg_kernel<0><<<dim3(1024, 2), dim3(256), 0, stream>>>(p1, q1);

    // layer 2 linears (K=256)
    GemmArgs g2;
    g2.d[0] = { h1p, wbf[6],  (const float*)d_in[19], z[0] };
    g2.d[1] = { h1q, wbf[7],  (const float*)d_in[23], z[1] };
    g2.d[2] = { h1q, wbf[8],  (const float*)d_in[25], z[2] };
    g2.d[3] = { h1q, wbf[9],  (const float*)d_in[21], z[3] };
    g2.d[4] = { h1p, wbf[10], (const float*)d_in[27], z[4] };
    g2.d[5] = { h1p, wbf[11], (const float*)d_in[29], z[5] };
    gemm6_kernel<256><<<dim3(64, 4, 6), dim3(256), 0, stream>>>(g2);

    float* outp = (float*)d_out;
    AggSide p2 = { z[0], z[1], z[2], idx0, cnt0, idx3, cnt3, nullptr, outp };
    AggSide q2 = { z[3], z[4], z[5], idx1, cnt1, idx2, cnt2, nullptr, outp + (size_t)8192 * 256 };
    agg_kernel<1><<<dim3(1024, 2), dim3(256), 0, stream>>>(p2, q2);
}